// Round 17
// baseline (149.667 us; speedup 1.0000x reference)
//
#include <hip/hip_runtime.h>

#define NPTS 8192
#define NB 4
#define KNN 16
#define DCH 64
#define CAP 128
#define WR 8

typedef float f32x2 __attribute__((ext_vector_type(2)));

// ws layout (bytes):
//   xq    : float4[NB*NPTS]   @ 0        (524288)  raw (x,y,z,|x|^2) -- queries, k3, k5
//   xsb4  : float4[NB*NPTS]   @ 524288   (524288)  candidates, SoA-by-4-block:
//           block k (cands 4k..4k+3) = [X4 | Y4 | Z4 | W4] with X=-2x, Y=-2y, Z=-2z, W=|c|^2
//   ibuf  : ushort[NB*NPTS][16] @ 1048576 (1048576) final knn ids per row
//   stats : double[54]        @ 2097152  (432, pad 512)
//   ss    : float[128]        @ 2097664
#define WS_XQ 0
#define WS_XS 524288
#define WS_IB 1048576
#define WS_ST 2097152
#define WS_SS 2097664

// v = qx*X + qy*Y + qz*Z + W  (= -2*dot(q,c)+|c|^2); d = v + |q|^2 row-const => same ranking.
// Packed: 2 candidates per op chain via v_pk_fma_f32. Identical expression in both passes
// => bit-identical values => selection consistency.
__device__ __forceinline__ f32x2 vkey2(f32x2 qx, f32x2 qy, f32x2 qz,
                                       f32x2 cx, f32x2 cy, f32x2 cz, f32x2 cw) {
    return __builtin_elementwise_fma(qx, cx,
           __builtin_elementwise_fma(qy, cy,
           __builtin_elementwise_fma(qz, cz, cw)));
}

__global__ __launch_bounds__(256) void k1_prep(const float* __restrict__ x, float4* __restrict__ xq,
                                               float* __restrict__ xsb) {
    int p = blockIdx.x * 256 + threadIdx.x;
    if (p >= NB * NPTS) return;
    float x0 = x[p * 3 + 0], x1 = x[p * 3 + 1], x2 = x[p * 3 + 2];
    float sq = __fmaf_rn(x0, x0, __fmaf_rn(x1, x1, x2 * x2));
    xq[p] = make_float4(x0, x1, x2, sq);
    int k = p >> 2, s = p & 3;
    size_t base = (size_t)k * 16 + s;
    xsb[base + 0]  = -2.0f * x0;
    xsb[base + 4]  = -2.0f * x1;
    xsb[base + 8]  = -2.0f * x2;
    xsb[base + 12] = sq;
}

// wave-per-8-rows exact KNN via threshold filter, packed-FP32 distance math.
// phase1: per-lane min over its 128-cand slice (4 cands/iter as 2 packed pairs; one base
//         pointer, imm offsets 0/16/32/48; next-iter prefetch; tail peeled).
// tau   : 16th smallest of the 64 lane-slice-minima via LDS rank-count (slice = disjoint
//         64-way cover of 8192 => >=16 distinct cands <= tau => tau >= d16, exact bound).
// phase2: rescan (same packed vkey), ballot-append all v <= tau.
// phase3: exact rank-count top-16 by (v, idx) -- matches top_k ties.
// LDS = 32KB buf + 8KB vmin = 40960 -> 4 blocks/CU.
__global__ __launch_bounds__(256, 4) void k2_knn(const float4* __restrict__ xq,
                                                 const float4* __restrict__ xs,
                                                 unsigned short* __restrict__ ibuf) {
    __shared__ float2 buf[4][WR][CAP];   // 32 KB
    __shared__ float vmin[4][WR][64];    // 8 KB
    const int wave = threadIdx.x >> 6;
    const int lane = threadIdx.x & 63;
    const int b = blockIdx.x >> 8;                 // 256 blocks per batch
    const int blkrow = (blockIdx.x & 255) * (4 * WR);
    const float4* xb = xq + b * NPTS;
    const float4* xc = xs + (size_t)b * NPTS;      // NPTS float4s per batch (SoA-by-4 blocks)
    const int rowbase = blkrow + wave * WR;

    // splat query components to packed pairs (loop-invariant; q.w unused in k2)
    f32x2 qx2[WR], qy2[WR], qz2[WR];
#pragma unroll
    for (int r = 0; r < WR; ++r) {
        float4 xi = xb[rowbase + r];   // broadcast loads
        qx2[r] = (f32x2){xi.x, xi.x};
        qy2[r] = (f32x2){xi.y, xi.y};
        qz2[r] = (f32x2){xi.z, xi.z};
    }

    // ---- phase 1: lane-slice minima (4 cands/iter = 2 packed pairs) ----
    float mna[WR], mnb[WR];
#pragma unroll
    for (int r = 0; r < WR; ++r) { mna[r] = 3.0e38f; mnb[r] = 3.0e38f; }

    {
        const float4* p = xc + lane * 4;
        float4 X = p[0], Y = p[1], Z = p[2], W = p[3];
        for (int c0 = 0; c0 < NPTS - 256; c0 += 256) {
            const float4* pn = p + 256;
            float4 Xn = pn[0], Yn = pn[1], Zn = pn[2], Wn = pn[3];
            f32x2 Xa = {X.x, X.y}, Xb = {X.z, X.w};
            f32x2 Ya = {Y.x, Y.y}, Yb = {Y.z, Y.w};
            f32x2 Za = {Z.x, Z.y}, Zb = {Z.z, Z.w};
            f32x2 Wa = {W.x, W.y}, Wb = {W.z, W.w};
#pragma unroll
            for (int r = 0; r < WR; ++r) {
                f32x2 va = vkey2(qx2[r], qy2[r], qz2[r], Xa, Ya, Za, Wa);
                f32x2 vb = vkey2(qx2[r], qy2[r], qz2[r], Xb, Yb, Zb, Wb);
                mna[r] = fminf(mna[r], fminf(va.x, vb.x));   // -> v_min3_f32
                mnb[r] = fminf(mnb[r], fminf(va.y, vb.y));
            }
            X = Xn; Y = Yn; Z = Zn; W = Wn; p = pn;
        }
        {   // peeled tail
            f32x2 Xa = {X.x, X.y}, Xb = {X.z, X.w};
            f32x2 Ya = {Y.x, Y.y}, Yb = {Y.z, Y.w};
            f32x2 Za = {Z.x, Z.y}, Zb = {Z.z, Z.w};
            f32x2 Wa = {W.x, W.y}, Wb = {W.z, W.w};
#pragma unroll
            for (int r = 0; r < WR; ++r) {
                f32x2 va = vkey2(qx2[r], qy2[r], qz2[r], Xa, Ya, Za, Wa);
                f32x2 vb = vkey2(qx2[r], qy2[r], qz2[r], Xb, Yb, Zb, Wb);
                mna[r] = fminf(mna[r], fminf(va.x, vb.x));
                mnb[r] = fminf(mnb[r], fminf(va.y, vb.y));
            }
        }
    }

    float mn[WR];
#pragma unroll
    for (int r = 0; r < WR; ++r) mn[r] = fminf(mna[r], mnb[r]);   // lane slice-min (128 cands)

    // ---- tau per row: 16th smallest of the 64 lane-minima ----
#pragma unroll
    for (int r = 0; r < WR; ++r) vmin[wave][r][lane] = mn[r];
    __syncthreads();   // hard fence: all vmin writes visible before the broadcast reads

    float tau[WR];
#pragma unroll
    for (int r = 0; r < WR; ++r) {
        float mine = mn[r];
        int rk = 0;
        const float4* vm4 = (const float4*)(&vmin[wave][r][0]);
#pragma unroll
        for (int q = 0; q < 16; ++q) {
            float4 vv = vm4[q];   // broadcast read, conflict-free
            int j0 = q * 4;
            rk += (vv.x < mine || (vv.x == mine && (j0 + 0) < lane)) ? 1 : 0;
            rk += (vv.y < mine || (vv.y == mine && (j0 + 1) < lane)) ? 1 : 0;
            rk += (vv.z < mine || (vv.z == mine && (j0 + 2) < lane)) ? 1 : 0;
            rk += (vv.w < mine || (vv.w == mine && (j0 + 3) < lane)) ? 1 : 0;
        }
        float v = (rk < KNN) ? mine : -3.0e38f;
#pragma unroll
        for (int o = 32; o > 0; o >>= 1) v = fmaxf(v, __shfl_xor(v, o));
        tau[r] = v;
    }

    // ---- phase 2: filtered collection (same packed vkey, ballot compaction) ----
    int cnt[WR];
#pragma unroll
    for (int r = 0; r < WR; ++r) cnt[r] = 0;

    {
        const float4* p = xc + lane * 4;
        float4 X = p[0], Y = p[1], Z = p[2], W = p[3];
        float fl4 = (float)(lane << 2);
        for (int c0 = 0; c0 < NPTS; c0 += 256) {
            bool last = (c0 >= NPTS - 256);
            float4 Xn, Yn, Zn, Wn;
            if (!last) {
                const float4* pn = p + 256;
                Xn = pn[0]; Yn = pn[1]; Zn = pn[2]; Wn = pn[3];
            }
            f32x2 Xa = {X.x, X.y}, Xb = {X.z, X.w};
            f32x2 Ya = {Y.x, Y.y}, Yb = {Y.z, Y.w};
            f32x2 Za = {Z.x, Z.y}, Zb = {Z.z, Z.w};
            f32x2 Wa = {W.x, W.y}, Wb = {W.z, W.w};
            float f0 = (float)c0 + fl4;
#pragma unroll
            for (int r = 0; r < WR; ++r) {
                f32x2 va = vkey2(qx2[r], qy2[r], qz2[r], Xa, Ya, Za, Wa);
                f32x2 vb = vkey2(qx2[r], qy2[r], qz2[r], Xb, Yb, Zb, Wb);
                float vs[4] = {va.x, va.y, vb.x, vb.y};   // slots s: cand = c0 + 4*lane + s
#pragma unroll
                for (int s = 0; s < 4; ++s) {
                    float v = vs[s];
                    bool pp = (v <= tau[r]);
                    unsigned long long m = __ballot(pp);
                    if (m) {
                        if (pp) {
                            int ofs = __builtin_amdgcn_mbcnt_hi((unsigned)(m >> 32),
                                      __builtin_amdgcn_mbcnt_lo((unsigned)m, 0));
                            int pos = cnt[r] + ofs;
                            if (pos < CAP) buf[wave][r][pos] = make_float2(v, f0 + (float)s);
                        }
                        cnt[r] += (int)__popcll(m);
                    }
                }
            }
            if (!last) { X = Xn; Y = Yn; Z = Zn; W = Wn; p += 256; }
        }
    }

    __syncthreads();   // hard ordering: all buf writes visible before phase 3 reads

    // ---- phase 3: exact top-16 of buffer by rank count ----
#pragma unroll
    for (int rr = 0; rr < WR; ++rr) {
        int n = cnt[rr];
        n = (n < CAP) ? n : CAP;
        int l1 = lane + 64;
        bool v0 = (lane < n), v1 = (l1 < n);
        float2 e0 = buf[wave][rr][v0 ? lane : 0];
        float2 e1 = buf[wave][rr][v1 ? l1 : 0];
        int r0 = 0, r1 = 0;
        for (int j = 0; j < n; ++j) {
            float2 fj = buf[wave][rr][j];   // broadcast read
            r0 += (fj.x < e0.x || (fj.x == e0.x && fj.y < e0.y)) ? 1 : 0;
            r1 += (fj.x < e1.x || (fj.x == e1.x && fj.y < e1.y)) ? 1 : 0;
        }
        size_t grow = (size_t)(b * NPTS + rowbase + rr) * KNN;
        if (v0 && r0 < KNN) ibuf[grow + r0] = (unsigned short)(int)e0.y;
        if (v1 && r1 < KNN) ibuf[grow + r1] = (unsigned short)(int)e1.y;
    }
}

// moments over the 16 selected neighbors: acc[0..8]=sum f, acc[9..53]=sum f_a f_c (upper tri)
__global__ __launch_bounds__(256) void k3_moments(const float4* __restrict__ xq,
                                                  const unsigned short* __restrict__ ibuf,
                                                  double* __restrict__ stats) {
    __shared__ float red[4][54];
    int p = blockIdx.x * 256 + threadIdx.x;
    int b = p >> 13;
    const float4* xb = xq + b * NPTS;
    const unsigned short* ib = ibuf + (size_t)p * KNN;
    float4 xi = xb[p & (NPTS - 1)];

    float acc[54];
#pragma unroll
    for (int i = 0; i < 54; ++i) acc[i] = 0.0f;

#pragma unroll
    for (int k = 0; k < KNN; ++k) {
        int j = ib[k];
        float4 cj = xb[j];
        float f[9] = {xi.x, xi.y, xi.z, cj.x - xi.x, cj.y - xi.y, cj.z - xi.z, cj.x, cj.y, cj.z};
        int t = 9;
#pragma unroll
        for (int a = 0; a < 9; ++a) {
            acc[a] += f[a];
#pragma unroll
            for (int c = a; c < 9; ++c) { acc[t] += f[a] * f[c]; ++t; }
        }
    }

#pragma unroll
    for (int i = 0; i < 54; ++i) {
        float v = acc[i];
        for (int o = 32; o > 0; o >>= 1) v += __shfl_down(v, o);
        acc[i] = v;
    }
    int lane = threadIdx.x & 63;
    int wv = threadIdx.x >> 6;
    if (lane == 0) {
#pragma unroll
        for (int i = 0; i < 54; ++i) red[wv][i] = acc[i];
    }
    __syncthreads();
    if (threadIdx.x < 54) {
        float s = red[0][threadIdx.x] + red[1][threadIdx.x] + red[2][threadIdx.x] + red[3][threadIdx.x];
        atomicAdd(&stats[threadIdx.x], (double)s);
    }
}

__global__ void k4_finalize(const double* __restrict__ stats, const float* __restrict__ W,
                            const float* __restrict__ bias, const float* __restrict__ gamma,
                            const float* __restrict__ beta, float* __restrict__ ss) {
    int d = threadIdx.x;
    if (d >= DCH) return;
    const double M = (double)NB * NPTS * KNN;  // 524288
    double w[9];
    for (int c = 0; c < 9; ++c) w[c] = (double)W[c * DCH + d];
    double mf[9];
    for (int a = 0; a < 9; ++a) mf[a] = stats[a] / M;
    double q1 = 0.0;
    for (int a = 0; a < 9; ++a) q1 += mf[a] * w[a];
    double q2 = 0.0;
    int t = 0;
    for (int a = 0; a < 9; ++a) {
        for (int c = a; c < 9; ++c) {
            double pv = stats[9 + t] / M;
            double term = pv * w[a] * w[c];
            q2 += (a == c) ? term : 2.0 * term;
            ++t;
        }
    }
    double bd = (double)bias[d];
    double mean = q1 + bd;
    double ehh = q2 + 2.0 * bd * q1 + bd * bd;
    double var = ehh - mean * mean;
    double sc = (double)gamma[d] / sqrt(var + 1e-5);
    double sh = (double)beta[d] + sc * (bd - mean);
    ss[d] = (float)sc;
    ss[DCH + d] = (float)sh;
}

// 8 threads per point, 8 channels each: h = f.W (W in regs), y = max_k relu(sc*h+sh)
__global__ __launch_bounds__(256) void k5_out(const float4* __restrict__ xq,
                                              const unsigned short* __restrict__ ibuf,
                                              const float* __restrict__ W, const float* __restrict__ ss,
                                              float* __restrict__ out) {
    __shared__ float Ws[9 * DCH];
    __shared__ float scs[DCH], shs[DCH];
    for (int i = threadIdx.x; i < 9 * DCH; i += 256) Ws[i] = W[i];
    if (threadIdx.x < DCH) {
        scs[threadIdx.x] = ss[threadIdx.x];
        shs[threadIdx.x] = ss[DCH + threadIdx.x];
    }
    __syncthreads();

    int pt = blockIdx.x * 32 + (threadIdx.x >> 3);
    int oc = (threadIdx.x & 7) * 8;
    int b = pt >> 13;
    const float4* xb = xq + b * NPTS;
    float4 xi = xb[pt & (NPTS - 1)];

    float w[9][8];
#pragma unroll
    for (int c = 0; c < 9; ++c)
#pragma unroll
        for (int d = 0; d < 8; ++d) w[c][d] = Ws[c * DCH + oc + d];
    float sc[8], sh[8], y[8];
#pragma unroll
    for (int d = 0; d < 8; ++d) {
        sc[d] = scs[oc + d];
        sh[d] = shs[oc + d];
        y[d] = 0.0f;
    }

    const unsigned short* ib = ibuf + (size_t)pt * KNN;
#pragma unroll
    for (int k = 0; k < KNN; ++k) {
        int j = ib[k];
        float4 cj = xb[j];
        float f[9] = {xi.x, xi.y, xi.z, cj.x - xi.x, cj.y - xi.y, cj.z - xi.z, cj.x, cj.y, cj.z};
        float h[8];
#pragma unroll
        for (int d = 0; d < 8; ++d) h[d] = 0.0f;
#pragma unroll
        for (int c = 0; c < 9; ++c)
#pragma unroll
            for (int d = 0; d < 8; ++d) h[d] = __fmaf_rn(f[c], w[c][d], h[d]);
#pragma unroll
        for (int d = 0; d < 8; ++d) {
            float v = __fmaf_rn(sc[d], h[d], sh[d]);
            y[d] = fmaxf(y[d], fmaxf(v, 0.0f));
        }
    }
    float4* o4 = (float4*)(out + (size_t)pt * DCH + oc);
    o4[0] = make_float4(y[0], y[1], y[2], y[3]);
    o4[1] = make_float4(y[4], y[5], y[6], y[7]);
}

extern "C" void kernel_launch(void* const* d_in, const int* in_sizes, int n_in,
                              void* d_out, int out_size, void* d_ws, size_t ws_size,
                              hipStream_t stream) {
    const float* x = (const float*)d_in[0];
    const float* W = (const float*)d_in[1];
    const float* bias = (const float*)d_in[2];
    const float* gamma = (const float*)d_in[3];
    const float* beta = (const float*)d_in[4];
    float* out = (float*)d_out;
    char* ws = (char*)d_ws;

    float4* xq = (float4*)(ws + WS_XQ);
    float4* xs = (float4*)(ws + WS_XS);
    unsigned short* ibuf = (unsigned short*)(ws + WS_IB);
    double* stats = (double*)(ws + WS_ST);
    float* ss = (float*)(ws + WS_SS);

    hipMemsetAsync(stats, 0, 54 * sizeof(double), stream);
    k1_prep<<<128, 256, 0, stream>>>(x, xq, (float*)xs);
    k2_knn<<<1024, 256, 0, stream>>>(xq, xs, ibuf);
    k3_moments<<<128, 256, 0, stream>>>(xq, ibuf, stats);
    k4_finalize<<<1, 64, 0, stream>>>(stats, W, bias, gamma, beta, ss);
    k5_out<<<1024, 256, 0, stream>>>(xq, ibuf, W, ss, out);
}

// Round 18
// 136.465 us; speedup vs baseline: 1.0967x; 1.0967x over previous
//
#include <hip/hip_runtime.h>

#define NPTS 8192
#define NB 4
#define KNN 16
#define DCH 64
#define CAP 128
#define WR 8

// ws layout (bytes):
//   xq4   : float4[NB*NPTS]  @ 0        (524288)   raw (x,y,z,|x|^2)  -- queries, k3, k5
//   xs4   : float4[NB*NPTS]  @ 524288   (524288)   scaled (-2x,-2y,-2z,|x|^2) -- k2 scans
//   ibuf  : ushort[NB*NPTS][16] @ 1048576 (1048576) final knn ids per row
//   stats : double[54]       @ 2097152  (432, pad 512)
//   ss    : float[128]       @ 2097664
#define WS_XQ 0
#define WS_XS 524288
#define WS_IB 1048576
#define WS_ST 2097152
#define WS_SS 2097664

// Selection key on prescaled candidate c' = (-2cx,-2cy,-2cz,|c|^2):
//   v = q.x*c'.x + q.y*c'.y + q.z*c'.z + c'.w = -2*dot(q,c) + |c|^2
// d = v + |q|^2 with |q|^2 constant per row => ranking by v == ranking by d.
__device__ __forceinline__ float vkey(float4 q, float4 c) {
    return __fmaf_rn(q.x, c.x, __fmaf_rn(q.y, c.y, __fmaf_rn(q.z, c.z, c.w)));
}

__global__ __launch_bounds__(256) void k1_prep(const float* __restrict__ x, float4* __restrict__ xq,
                                               float4* __restrict__ xs) {
    int p = blockIdx.x * 256 + threadIdx.x;
    if (p >= NB * NPTS) return;
    float x0 = x[p * 3 + 0], x1 = x[p * 3 + 1], x2 = x[p * 3 + 2];
    float sq = __fmaf_rn(x0, x0, __fmaf_rn(x1, x1, x2 * x2));
    xq[p] = make_float4(x0, x1, x2, sq);
    xs[p] = make_float4(-2.0f * x0, -2.0f * x1, -2.0f * x2, sq);
}

// wave-per-8-rows exact KNN via threshold filter.
// All scan loads share ONE base pointer with imm offsets 0/1024/2048/3072 (13-bit range);
// next-iter prefetch via pn=p+256. 4 cands/lane/iter, final iteration peeled (no guards,
// no wrap arithmetic). tau/ballot/phase-3 logic identical to the R9/R13-proven kernel.
__global__ __launch_bounds__(256, 4) void k2_knn(const float4* __restrict__ xq,
                                                 const float4* __restrict__ xs,
                                                 unsigned short* __restrict__ ibuf) {
    __shared__ float2 buf[4][WR][CAP];   // 32 KB
    __shared__ float vmin[4][WR][64];    // 8 KB
    const int wave = threadIdx.x >> 6;
    const int lane = threadIdx.x & 63;
    const int b = blockIdx.x >> 8;                 // 256 blocks per batch
    const int blkrow = (blockIdx.x & 255) * (4 * WR);
    const float4* xb = xq + b * NPTS;
    const float4* xc = xs + b * NPTS;
    const int rowbase = blkrow + wave * WR;

    float4 xi[WR];
#pragma unroll
    for (int r = 0; r < WR; ++r) xi[r] = xb[rowbase + r];   // raw queries, broadcast loads

    // ---- phase 1: lane-slice minima (4 cands/iter, imm-offset loads, peeled tail) ----
    float mn[WR];
#pragma unroll
    for (int r = 0; r < WR; ++r) mn[r] = 3.0e38f;

    {
        const float4* p = xc + lane;
        float4 a0 = p[0], a1 = p[64], a2 = p[128], a3 = p[192];
        for (int c0 = 0; c0 < NPTS - 256; c0 += 256) {
            const float4* pn = p + 256;
            float4 b0 = pn[0], b1 = pn[64], b2 = pn[128], b3 = pn[192];
#pragma unroll
            for (int r = 0; r < WR; ++r) {
                float v0 = vkey(xi[r], a0);
                float v1 = vkey(xi[r], a1);
                float v2 = vkey(xi[r], a2);
                float v3 = vkey(xi[r], a3);
                mn[r] = fminf(mn[r], fminf(v0, v1));   // -> v_min3_f32
                mn[r] = fminf(mn[r], fminf(v2, v3));
            }
            a0 = b0; a1 = b1; a2 = b2; a3 = b3; p = pn;
        }
#pragma unroll
        for (int r = 0; r < WR; ++r) {
            float v0 = vkey(xi[r], a0);
            float v1 = vkey(xi[r], a1);
            float v2 = vkey(xi[r], a2);
            float v3 = vkey(xi[r], a3);
            mn[r] = fminf(mn[r], fminf(v0, v1));
            mn[r] = fminf(mn[r], fminf(v2, v3));
        }
    }

    // ---- tau per row: 16th smallest of the 64 lane-minima ----
#pragma unroll
    for (int r = 0; r < WR; ++r) vmin[wave][r][lane] = mn[r];
    __syncthreads();   // hard fence: all vmin writes visible before the broadcast reads

    float tau[WR];
#pragma unroll
    for (int r = 0; r < WR; ++r) {
        float mine = mn[r];
        int rk = 0;
        const float4* vm4 = (const float4*)(&vmin[wave][r][0]);
#pragma unroll
        for (int q = 0; q < 16; ++q) {
            float4 vv = vm4[q];   // broadcast read, conflict-free
            int j0 = q * 4;
            rk += (vv.x < mine || (vv.x == mine && (j0 + 0) < lane)) ? 1 : 0;
            rk += (vv.y < mine || (vv.y == mine && (j0 + 1) < lane)) ? 1 : 0;
            rk += (vv.z < mine || (vv.z == mine && (j0 + 2) < lane)) ? 1 : 0;
            rk += (vv.w < mine || (vv.w == mine && (j0 + 3) < lane)) ? 1 : 0;
        }
        // lanes with rk<16 hold exactly the 16 smallest (lex); tau = max of their values
        float v = (rk < KNN) ? mine : -3.0e38f;
#pragma unroll
        for (int o = 32; o > 0; o >>= 1) v = fmaxf(v, __shfl_xor(v, o));
        tau[r] = v;
    }

    // ---- phase 2: filtered collection (same pipelined structure, ballot compaction) ----
    int cnt[WR];
#pragma unroll
    for (int r = 0; r < WR; ++r) cnt[r] = 0;

    {
        const float4* p = xc + lane;
        float4 a0 = p[0], a1 = p[64], a2 = p[128], a3 = p[192];
        float fl = (float)lane;
        for (int c0 = 0; c0 < NPTS; c0 += 256) {
            bool last = (c0 >= NPTS - 256);
            float4 b0, b1, b2, b3;
            if (!last) {
                const float4* pn = p + 256;
                b0 = pn[0]; b1 = pn[64]; b2 = pn[128]; b3 = pn[192];
            }
            float f0 = (float)c0 + fl;
#pragma unroll
            for (int r = 0; r < WR; ++r) {
                float v0 = vkey(xi[r], a0);
                float v1 = vkey(xi[r], a1);
                float v2 = vkey(xi[r], a2);
                float v3 = vkey(xi[r], a3);
#pragma unroll
                for (int s = 0; s < 4; ++s) {
                    float v = (s == 0) ? v0 : (s == 1) ? v1 : (s == 2) ? v2 : v3;
                    bool pp = (v <= tau[r]);
                    unsigned long long m = __ballot(pp);
                    if (m) {
                        if (pp) {
                            int ofs = __builtin_amdgcn_mbcnt_hi((unsigned)(m >> 32),
                                      __builtin_amdgcn_mbcnt_lo((unsigned)m, 0));
                            int pos = cnt[r] + ofs;
                            if (pos < CAP) buf[wave][r][pos] = make_float2(v, f0 + (float)(s * 64));
                        }
                        cnt[r] += (int)__popcll(m);
                    }
                }
            }
            if (!last) { a0 = b0; a1 = b1; a2 = b2; a3 = b3; p += 256; }
        }
    }

    __syncthreads();   // hard ordering: all buf writes visible before phase 3 reads

    // ---- phase 3: exact top-16 of buffer by rank count ----
#pragma unroll
    for (int rr = 0; rr < WR; ++rr) {
        int n = cnt[rr];
        n = (n < CAP) ? n : CAP;
        int l1 = lane + 64;
        bool v0 = (lane < n), v1 = (l1 < n);
        float2 e0 = buf[wave][rr][v0 ? lane : 0];
        float2 e1 = buf[wave][rr][v1 ? l1 : 0];
        int r0 = 0, r1 = 0;
        for (int j = 0; j < n; ++j) {
            float2 fj = buf[wave][rr][j];   // broadcast read
            r0 += (fj.x < e0.x || (fj.x == e0.x && fj.y < e0.y)) ? 1 : 0;
            r1 += (fj.x < e1.x || (fj.x == e1.x && fj.y < e1.y)) ? 1 : 0;
        }
        size_t grow = (size_t)(b * NPTS + rowbase + rr) * KNN;
        if (v0 && r0 < KNN) ibuf[grow + r0] = (unsigned short)(int)e0.y;
        if (v1 && r1 < KNN) ibuf[grow + r1] = (unsigned short)(int)e1.y;
    }
}

// moments over the 16 selected neighbors: acc[0..8]=sum f, acc[9..53]=sum f_a f_c (upper tri)
__global__ __launch_bounds__(256) void k3_moments(const float4* __restrict__ xq,
                                                  const unsigned short* __restrict__ ibuf,
                                                  double* __restrict__ stats) {
    __shared__ float red[4][54];
    int p = blockIdx.x * 256 + threadIdx.x;
    int b = p >> 13;
    const float4* xb = xq + b * NPTS;
    const unsigned short* ib = ibuf + (size_t)p * KNN;
    float4 xi = xb[p & (NPTS - 1)];

    float acc[54];
#pragma unroll
    for (int i = 0; i < 54; ++i) acc[i] = 0.0f;

#pragma unroll
    for (int k = 0; k < KNN; ++k) {
        int j = ib[k];
        float4 cj = xb[j];
        float f[9] = {xi.x, xi.y, xi.z, cj.x - xi.x, cj.y - xi.y, cj.z - xi.z, cj.x, cj.y, cj.z};
        int t = 9;
#pragma unroll
        for (int a = 0; a < 9; ++a) {
            acc[a] += f[a];
#pragma unroll
            for (int c = a; c < 9; ++c) { acc[t] += f[a] * f[c]; ++t; }
        }
    }

#pragma unroll
    for (int i = 0; i < 54; ++i) {
        float v = acc[i];
        for (int o = 32; o > 0; o >>= 1) v += __shfl_down(v, o);
        acc[i] = v;
    }
    int lane = threadIdx.x & 63;
    int wv = threadIdx.x >> 6;
    if (lane == 0) {
#pragma unroll
        for (int i = 0; i < 54; ++i) red[wv][i] = acc[i];
    }
    __syncthreads();
    if (threadIdx.x < 54) {
        float s = red[0][threadIdx.x] + red[1][threadIdx.x] + red[2][threadIdx.x] + red[3][threadIdx.x];
        atomicAdd(&stats[threadIdx.x], (double)s);
    }
}

__global__ void k4_finalize(const double* __restrict__ stats, const float* __restrict__ W,
                            const float* __restrict__ bias, const float* __restrict__ gamma,
                            const float* __restrict__ beta, float* __restrict__ ss) {
    int d = threadIdx.x;
    if (d >= DCH) return;
    const double M = (double)NB * NPTS * KNN;  // 524288
    double w[9];
    for (int c = 0; c < 9; ++c) w[c] = (double)W[c * DCH + d];
    double mf[9];
    for (int a = 0; a < 9; ++a) mf[a] = stats[a] / M;
    double q1 = 0.0;
    for (int a = 0; a < 9; ++a) q1 += mf[a] * w[a];
    double q2 = 0.0;
    int t = 0;
    for (int a = 0; a < 9; ++a) {
        for (int c = a; c < 9; ++c) {
            double pv = stats[9 + t] / M;
            double term = pv * w[a] * w[c];
            q2 += (a == c) ? term : 2.0 * term;
            ++t;
        }
    }
    double bd = (double)bias[d];
    double mean = q1 + bd;
    double ehh = q2 + 2.0 * bd * q1 + bd * bd;
    double var = ehh - mean * mean;
    double sc = (double)gamma[d] / sqrt(var + 1e-5);
    double sh = (double)beta[d] + sc * (bd - mean);
    ss[d] = (float)sc;
    ss[DCH + d] = (float)sh;
}

// 8 threads per point, 8 channels each: h = f.W (W in regs), y = max_k relu(sc*h+sh)
__global__ __launch_bounds__(256) void k5_out(const float4* __restrict__ xq,
                                              const unsigned short* __restrict__ ibuf,
                                              const float* __restrict__ W, const float* __restrict__ ss,
                                              float* __restrict__ out) {
    __shared__ float Ws[9 * DCH];
    __shared__ float scs[DCH], shs[DCH];
    for (int i = threadIdx.x; i < 9 * DCH; i += 256) Ws[i] = W[i];
    if (threadIdx.x < DCH) {
        scs[threadIdx.x] = ss[threadIdx.x];
        shs[threadIdx.x] = ss[DCH + threadIdx.x];
    }
    __syncthreads();

    int pt = blockIdx.x * 32 + (threadIdx.x >> 3);
    int oc = (threadIdx.x & 7) * 8;
    int b = pt >> 13;
    const float4* xb = xq + b * NPTS;
    float4 xi = xb[pt & (NPTS - 1)];

    float w[9][8];
#pragma unroll
    for (int c = 0; c < 9; ++c)
#pragma unroll
        for (int d = 0; d < 8; ++d) w[c][d] = Ws[c * DCH + oc + d];
    float sc[8], sh[8], y[8];
#pragma unroll
    for (int d = 0; d < 8; ++d) {
        sc[d] = scs[oc + d];
        sh[d] = shs[oc + d];
        y[d] = 0.0f;
    }

    const unsigned short* ib = ibuf + (size_t)pt * KNN;
#pragma unroll
    for (int k = 0; k < KNN; ++k) {
        int j = ib[k];
        float4 cj = xb[j];
        float f[9] = {xi.x, xi.y, xi.z, cj.x - xi.x, cj.y - xi.y, cj.z - xi.z, cj.x, cj.y, cj.z};
        float h[8];
#pragma unroll
        for (int d = 0; d < 8; ++d) h[d] = 0.0f;
#pragma unroll
        for (int c = 0; c < 9; ++c)
#pragma unroll
            for (int d = 0; d < 8; ++d) h[d] = __fmaf_rn(f[c], w[c][d], h[d]);
#pragma unroll
        for (int d = 0; d < 8; ++d) {
            float v = __fmaf_rn(sc[d], h[d], sh[d]);
            y[d] = fmaxf(y[d], fmaxf(v, 0.0f));
        }
    }
    float4* o4 = (float4*)(out + (size_t)pt * DCH + oc);
    o4[0] = make_float4(y[0], y[1], y[2], y[3]);
    o4[1] = make_float4(y[4], y[5], y[6], y[7]);
}

extern "C" void kernel_launch(void* const* d_in, const int* in_sizes, int n_in,
                              void* d_out, int out_size, void* d_ws, size_t ws_size,
                              hipStream_t stream) {
    const float* x = (const float*)d_in[0];
    const float* W = (const float*)d_in[1];
    const float* bias = (const float*)d_in[2];
    const float* gamma = (const float*)d_in[3];
    const float* beta = (const float*)d_in[4];
    float* out = (float*)d_out;
    char* ws = (char*)d_ws;

    float4* xq = (float4*)(ws + WS_XQ);
    float4* xs = (float4*)(ws + WS_XS);
    unsigned short* ibuf = (unsigned short*)(ws + WS_IB);
    double* stats = (double*)(ws + WS_ST);
    float* ss = (float*)(ws + WS_SS);

    hipMemsetAsync(stats, 0, 54 * sizeof(double), stream);
    k1_prep<<<128, 256, 0, stream>>>(x, xq, xs);
    k2_knn<<<1024, 256, 0, stream>>>(xq, xs, ibuf);
    k3_moments<<<128, 256, 0, stream>>>(xq, ibuf, stats);
    k4_finalize<<<1, 64, 0, stream>>>(stats, W, bias, gamma, beta, ss);
    k5_out<<<1024, 256, 0, stream>>>(xq, ibuf, W, ss, out);
}